// Round 1
// baseline (10941.413 us; speedup 1.0000x reference)
//
#include <hip/hip_runtime.h>
#include <hip/hip_bf16.h>

#define N_NODES 100000
#define N_EDGES 640000
#define DD 128
#define DE 32

__device__ __forceinline__ float gelu_f(float x) {
    return 0.5f * x * (1.0f + erff(x * 0.70710678118654752f));
}

__device__ __forceinline__ void fma16(float a, const float4* Wr, float* acc) {
#pragma unroll
    for (int t = 0; t < 4; t++) {
        float4 w = Wr[t];
        acc[t*4+0] += a*w.x; acc[t*4+1] += a*w.y;
        acc[t*4+2] += a*w.z; acc[t*4+3] += a*w.w;
    }
}

// ---------------- CSR build ----------------
__global__ void k_count(const int* __restrict__ ei, int* __restrict__ cnt) {
    int e = blockIdx.x * blockDim.x + threadIdx.x;
    if (e < N_EDGES) atomicAdd(&cnt[ei[N_EDGES + e]], 1);
}

__global__ void k_scan(const int* __restrict__ cnt, int* __restrict__ rowstart) {
    __shared__ int part[1024];
    int t = threadIdx.x;
    const int chunk = (N_NODES + 1023) / 1024;  // 98
    int lo = t * chunk, hi = min(lo + chunk, N_NODES);
    int s = 0;
    for (int i = lo; i < hi; i++) s += cnt[i];
    part[t] = s;
    __syncthreads();
    for (int off = 1; off < 1024; off <<= 1) {
        int v = (t >= off) ? part[t - off] : 0;
        __syncthreads();
        part[t] += v;
        __syncthreads();
    }
    int run = (t == 0) ? 0 : part[t - 1];
    for (int i = lo; i < hi; i++) { rowstart[i] = run; run += cnt[i]; }
    if (lo < N_NODES && hi == N_NODES) rowstart[N_NODES] = run;
}

__global__ void k_cursor(const int* __restrict__ rowstart, int* __restrict__ cursor) {
    int n = blockIdx.x * blockDim.x + threadIdx.x;
    if (n < N_NODES) cursor[n] = rowstart[n];
}

__global__ void k_scatter(const int* __restrict__ ei, int* __restrict__ cursor,
                          int* __restrict__ edge_order) {
    int e = blockIdx.x * blockDim.x + threadIdx.x;
    if (e < N_EDGES) {
        int pos = atomicAdd(&cursor[ei[N_EDGES + e]], 1);
        edge_order[pos] = e;
    }
}

// ---------------- composite edge weights ----------------
// We1[l][c][j] = sum_k edge_w[c][k]*msg_w1[l][k][j]
// bc[l][j]    = sum_k edge_b[k]*msg_w1[l][k][j] + msg_b1[l][j]
__global__ void k_prep(const float* __restrict__ edge_w, const float* __restrict__ edge_b,
                       const float* __restrict__ msg_w1, const float* __restrict__ msg_b1,
                       float* __restrict__ We1, float* __restrict__ bc) {
    int j = threadIdx.x;        // 128
    int c = blockIdx.x;         // 0..32 (32 = bias row)
    int l = blockIdx.y;         // 0..2
    const float* w1 = msg_w1 + (size_t)l * DD * DD;
    if (c < DE) {
        float s = 0.0f;
        for (int k = 0; k < DD; k++) s += edge_w[c*DD + k] * w1[k*DD + j];
        We1[((size_t)l*DE + c)*DD + j] = s;
    } else {
        float s = msg_b1[l*DD + j];
        for (int k = 0; k < DD; k++) s += edge_b[k] * w1[k*DD + j];
        bc[l*DD + j] = s;
    }
}

// ---------------- generic [M,128]@[128,128]+bias GEMM, 32 rows/block ----------------
__global__ __launch_bounds__(256) void k_gemm128(const float* __restrict__ A,
                                                 const float* __restrict__ W,
                                                 const float* __restrict__ bias,
                                                 float* __restrict__ C) {
    __shared__ float As[32][129];
    int tid = threadIdx.x;
    size_t base = (size_t)blockIdx.x * 32;
    const float4* Ag = (const float4*)(A + base * DD);
#pragma unroll
    for (int i = 0; i < 4; i++) {
        int idx = tid + i * 256;
        int r = idx >> 5, c = idx & 31;
        float4 v = Ag[idx];
        As[r][c*4+0] = v.x; As[r][c*4+1] = v.y; As[r][c*4+2] = v.z; As[r][c*4+3] = v.w;
    }
    __syncthreads();
    int r = tid >> 3, jb = (tid & 7) << 4;
    float acc[16];
#pragma unroll
    for (int i = 0; i < 16; i++) acc[i] = bias ? bias[jb + i] : 0.0f;
#pragma unroll 4
    for (int k = 0; k < DD; k++) {
        float a = As[r][k];
        fma16(a, (const float4*)(W + (size_t)k * DD + jb), acc);
    }
    float4* Cp = (float4*)(C + (base + r) * DD + jb);
#pragma unroll
    for (int t = 0; t < 4; t++) Cp[t] = make_float4(acc[t*4], acc[t*4+1], acc[t*4+2], acc[t*4+3]);
}

// ---------------- edge aggregation: one block (128 thr) per node ----------------
// aggh[n][j] = (1/max(deg,1)) * sum_{e: dst=n} gelu( nodeW1[src[e]][j] + bc[j]
//                                                    + sum_c edge_attr[e][c]*We1[c][j] )
__global__ __launch_bounds__(128) void k_edge_agg(const float* __restrict__ nodeW1,
                                                  const float* __restrict__ edge_attr,
                                                  const int* __restrict__ ei,
                                                  const int* __restrict__ rowstart,
                                                  const int* __restrict__ edge_order,
                                                  const float* __restrict__ We1,
                                                  const float* __restrict__ bc,
                                                  float* __restrict__ aggh) {
    __shared__ float Wl[DE][DD];
    __shared__ float bcl[DD];
    __shared__ float ea[DE];
    int j = threadIdx.x;
    int n = blockIdx.x;
#pragma unroll
    for (int c = 0; c < DE; c++) Wl[c][j] = We1[c*DD + j];
    bcl[j] = bc[j];
    int rs = rowstart[n], re = rowstart[n + 1];
    float acc = 0.0f;
    for (int idx = rs; idx < re; idx++) {
        __syncthreads();                 // protect ea reuse (also covers Wl on iter 0)
        int e = edge_order[idx];
        if (j < DE) ea[j] = edge_attr[(size_t)e * DE + j];
        __syncthreads();
        int s = ei[e];                   // src
        float v = nodeW1[(size_t)s * DD + j] + bcl[j];
#pragma unroll
        for (int c = 0; c < DE; c++) v += ea[c] * Wl[c][j];
        acc += gelu_f(v);
    }
    int deg = re - rs;
    float inv = (deg > 0) ? (1.0f / (float)deg) : 0.0f;
    aggh[(size_t)n * DD + j] = acc * inv;
}

// ---------------- fused node update: agg@W2+b2 -> gelu(@Wu1+b) -> @Wu2+b -> resid+LN ----------------
__global__ __launch_bounds__(256) void k_node_update(
    const float* __restrict__ aggh, float* __restrict__ node,
    const int* __restrict__ rowstart,
    const float* __restrict__ w2, const float* __restrict__ b2,
    const float* __restrict__ wu1, const float* __restrict__ bu1,
    const float* __restrict__ wu2, const float* __restrict__ bu2,
    const float* __restrict__ lg, const float* __restrict__ lb) {
    __shared__ float A[32][129];
    __shared__ float B[32][129];
    __shared__ float T[32][257];
    __shared__ float bf[32];
    int tid = threadIdx.x;
    size_t base = (size_t)blockIdx.x * 32;
    const float4* Ag = (const float4*)(aggh + base * DD);
#pragma unroll
    for (int i = 0; i < 4; i++) {
        int idx = tid + i * 256;
        int r = idx >> 5, c = idx & 31;
        float4 v = Ag[idx];
        A[r][c*4+0] = v.x; A[r][c*4+1] = v.y; A[r][c*4+2] = v.z; A[r][c*4+3] = v.w;
    }
    if (tid < 32) {
        int n = (int)base + tid;
        bf[tid] = (rowstart[n + 1] - rowstart[n]) > 0 ? 1.0f : 0.0f;
    }
    __syncthreads();
    int r = tid >> 3, q = tid & 7;
    // stage 1: B = A @ w2 + [deg>0]*b2
    {
        int jb = q * 16;
        float acc[16];
        float f = bf[r];
#pragma unroll
        for (int i = 0; i < 16; i++) acc[i] = f * b2[jb + i];
#pragma unroll 4
        for (int k = 0; k < DD; k++)
            fma16(A[r][k], (const float4*)(w2 + (size_t)k * DD + jb), acc);
#pragma unroll
        for (int i = 0; i < 16; i++) B[r][jb + i] = acc[i];
    }
    __syncthreads();
    // stage 2: T = gelu(B @ wu1 + bu1)   (DOUT=256)
    {
        int jb = q * 32;
        float acc[32];
#pragma unroll
        for (int i = 0; i < 32; i++) acc[i] = bu1[jb + i];
#pragma unroll 2
        for (int k = 0; k < DD; k++) {
            float a = B[r][k];
            const float4* Wr = (const float4*)(wu1 + (size_t)k * 256 + jb);
#pragma unroll
            for (int t = 0; t < 8; t++) {
                float4 w = Wr[t];
                acc[t*4+0] += a*w.x; acc[t*4+1] += a*w.y;
                acc[t*4+2] += a*w.z; acc[t*4+3] += a*w.w;
            }
        }
#pragma unroll
        for (int i = 0; i < 32; i++) T[r][jb + i] = gelu_f(acc[i]);
    }
    __syncthreads();
    // stage 3: u = T @ wu2 + bu2; x = node + u; LN(x)*lg+lb
    {
        int jb = q * 16;
        float acc[16];
#pragma unroll
        for (int i = 0; i < 16; i++) acc[i] = bu2[jb + i];
#pragma unroll 4
        for (int k = 0; k < 256; k++)
            fma16(T[r][k], (const float4*)(wu2 + (size_t)k * DD + jb), acc);
        size_t row = base + r;
        float x[16];
#pragma unroll
        for (int i = 0; i < 16; i++) x[i] = node[row * DD + jb + i] + acc[i];
        float s = 0.0f;
#pragma unroll
        for (int i = 0; i < 16; i++) s += x[i];
        s += __shfl_xor(s, 1); s += __shfl_xor(s, 2); s += __shfl_xor(s, 4);
        float m = s * (1.0f / 128.0f);
        float vv = 0.0f;
#pragma unroll
        for (int i = 0; i < 16; i++) { float d = x[i] - m; vv += d * d; }
        vv += __shfl_xor(vv, 1); vv += __shfl_xor(vv, 2); vv += __shfl_xor(vv, 4);
        float inv = rsqrtf(vv * (1.0f / 128.0f) + 1e-5f);
#pragma unroll
        for (int i = 0; i < 16; i++)
            node[row * DD + jb + i] = (x[i] - m) * inv * lg[jb + i] + lb[jb + i];
    }
}

// ---------------- pooling ----------------
__global__ void k_pool_partial(const float* __restrict__ node, float* __restrict__ partial) {
    int seg = blockIdx.x, chunk = blockIdx.y, j = threadIdx.x;
    int segbase = seg * 14286;
    int segcnt = (seg == 6) ? 14284 : 14286;
    int per = (segcnt + 15) / 16;
    int lo = chunk * per, hi = min(lo + per, segcnt);
    float s = 0.0f;
    for (int r = lo; r < hi; r++) s += node[(size_t)(segbase + r) * DD + j];
    partial[(seg * 16 + chunk) * DD + j] = s;
}

__global__ void k_pool_final(const float* __restrict__ partial, const float* __restrict__ g,
                             const float* __restrict__ b, float* __restrict__ out) {
    __shared__ float red[128];
    int j = threadIdx.x;
    float tok[8];
    float tot = 0.0f;
#pragma unroll
    for (int s = 0; s < 7; s++) {
        float v = 0.0f;
        for (int c = 0; c < 16; c++) v += partial[(s * 16 + c) * DD + j];
        tok[1 + s] = v / ((s == 6) ? 14284.0f : 14286.0f);
        tot += v;
    }
    tok[0] = tot / 100000.0f;
    for (int t = 0; t < 8; t++) {
        float x = tok[t];
        red[j] = x; __syncthreads();
        for (int off = 64; off > 0; off >>= 1) {
            if (j < off) red[j] += red[j + off];
            __syncthreads();
        }
        float m = red[0] / 128.0f;
        __syncthreads();
        float d = x - m;
        red[j] = d * d; __syncthreads();
        for (int off = 64; off > 0; off >>= 1) {
            if (j < off) red[j] += red[j + off];
            __syncthreads();
        }
        float var = red[0] / 128.0f;
        __syncthreads();
        out[t * DD + j] = d * rsqrtf(var + 1e-5f) * g[j] + b[j];
    }
}

extern "C" void kernel_launch(void* const* d_in, const int* in_sizes, int n_in,
                              void* d_out, int out_size, void* d_ws, size_t ws_size,
                              hipStream_t stream) {
    const float* x         = (const float*)d_in[0];
    const int*   ei        = (const int*)d_in[1];     // [2,E] int32 (JAX default x64 off)
    const float* edge_attr = (const float*)d_in[2];
    const float* node_w    = (const float*)d_in[3];
    const float* node_b    = (const float*)d_in[4];
    const float* edge_w    = (const float*)d_in[5];
    const float* edge_b    = (const float*)d_in[6];
    const float* msg_w1    = (const float*)d_in[7];
    const float* msg_b1    = (const float*)d_in[8];
    const float* msg_w2    = (const float*)d_in[9];
    const float* msg_b2    = (const float*)d_in[10];
    const float* upd_w1    = (const float*)d_in[11];
    const float* upd_b1    = (const float*)d_in[12];
    const float* upd_w2    = (const float*)d_in[13];
    const float* upd_b2    = (const float*)d_in[14];
    const float* ln_g      = (const float*)d_in[15];
    const float* ln_b      = (const float*)d_in[16];
    const float* out_g     = (const float*)d_in[17];
    const float* out_b     = (const float*)d_in[18];
    float* out = (float*)d_out;

    // workspace layout (~158 MB)
    float* node    = (float*)d_ws;                       // N*128
    float* nodeW1  = node + (size_t)N_NODES * DD;        // N*128
    float* aggh    = nodeW1 + (size_t)N_NODES * DD;      // N*128
    float* We1     = aggh + (size_t)N_NODES * DD;        // 3*32*128
    float* bc      = We1 + 3 * DE * DD;                  // 3*128
    float* partial = bc + 3 * DD;                        // 7*16*128
    int* cnt       = (int*)(partial + 7 * 16 * DD);      // N
    int* rowstart  = cnt + N_NODES;                      // N+1
    int* cursor    = rowstart + N_NODES + 1;             // N
    int* edge_order= cursor + N_NODES;                   // E

    hipMemsetAsync(cnt, 0, N_NODES * sizeof(int), stream);
    k_count  <<<(N_EDGES + 255) / 256, 256, 0, stream>>>(ei, cnt);
    k_scan   <<<1, 1024, 0, stream>>>(cnt, rowstart);
    k_cursor <<<(N_NODES + 255) / 256, 256, 0, stream>>>(rowstart, cursor);
    k_scatter<<<(N_EDGES + 255) / 256, 256, 0, stream>>>(ei, cursor, edge_order);
    k_prep   <<<dim3(DE + 1, 3), DD, 0, stream>>>(edge_w, edge_b, msg_w1, msg_b1, We1, bc);

    // node embedding: node = x @ node_w + node_b
    k_gemm128<<<N_NODES / 32, 256, 0, stream>>>(x, node_w, node_b, node);

    for (int l = 0; l < 3; l++) {
        k_gemm128<<<N_NODES / 32, 256, 0, stream>>>(node, msg_w1 + (size_t)l * DD * DD, nullptr, nodeW1);
        k_edge_agg<<<N_NODES, 128, 0, stream>>>(nodeW1, edge_attr, ei, rowstart, edge_order,
                                                We1 + (size_t)l * DE * DD, bc + (size_t)l * DD, aggh);
        k_node_update<<<N_NODES / 32, 256, 0, stream>>>(aggh, node, rowstart,
            msg_w2 + (size_t)l * DD * DD, msg_b2 + (size_t)l * DD,
            upd_w1 + (size_t)l * DD * 256, upd_b1 + (size_t)l * 256,
            upd_w2 + (size_t)l * 256 * DD, upd_b2 + (size_t)l * DD,
            ln_g + (size_t)l * DD, ln_b + (size_t)l * DD);
    }

    k_pool_partial<<<dim3(7, 16), DD, 0, stream>>>(node, partial);
    k_pool_final  <<<1, DD, 0, stream>>>(partial, out_g, out_b, out);
}

// Round 3
// 1898.559 us; speedup vs baseline: 5.7630x; 5.7630x over previous
//
#include <hip/hip_runtime.h>
#include <hip/hip_bf16.h>

#define N_NODES 100000
#define N_EDGES 640000
#define DD 128
#define DE 32

typedef __attribute__((ext_vector_type(8))) short bf8v;
typedef __attribute__((ext_vector_type(4))) float f4v;

__device__ __forceinline__ float gelu_f(float x) {
    return 0.5f * x * (1.0f + erff(x * 0.70710678118654752f));
}
__device__ __forceinline__ float bf2f(ushort u) {
    union { uint u; float f; } t; t.u = ((uint)u) << 16; return t.f;
}
__device__ __forceinline__ ushort f2bf(float f) {
    union { float f; uint u; } t; t.f = f;
    uint r = (t.u + 0x7fffu + ((t.u >> 16) & 1u)) >> 16;
    return (ushort)r;
}

// ---------------- CSR build ----------------
__global__ void k_count(const int* __restrict__ ei, int* __restrict__ cnt) {
    int e = blockIdx.x * blockDim.x + threadIdx.x;
    if (e < N_EDGES) atomicAdd(&cnt[ei[N_EDGES + e]], 1);
}

__global__ void k_scan(const int* __restrict__ cnt, int* __restrict__ rowstart) {
    __shared__ int part[1024];
    int t = threadIdx.x;
    const int chunk = (N_NODES + 1023) / 1024;
    int lo = t * chunk, hi = min(lo + chunk, N_NODES);
    int s = 0;
    for (int i = lo; i < hi; i++) s += cnt[i];
    part[t] = s;
    __syncthreads();
    for (int off = 1; off < 1024; off <<= 1) {
        int v = (t >= off) ? part[t - off] : 0;
        __syncthreads();
        part[t] += v;
        __syncthreads();
    }
    int run = (t == 0) ? 0 : part[t - 1];
    for (int i = lo; i < hi; i++) { rowstart[i] = run; run += cnt[i]; }
    if (lo < N_NODES && hi == N_NODES) rowstart[N_NODES] = run;
}

__global__ void k_cursor(const int* __restrict__ rowstart, int* __restrict__ cursor) {
    int n = blockIdx.x * blockDim.x + threadIdx.x;
    if (n < N_NODES) cursor[n] = rowstart[n];
}

__global__ void k_scatter(const int* __restrict__ ei, int* __restrict__ cursor,
                          int* __restrict__ edge_order) {
    int e = blockIdx.x * blockDim.x + threadIdx.x;
    if (e < N_EDGES) {
        int pos = atomicAdd(&cursor[ei[N_EDGES + e]], 1);
        edge_order[pos] = e;
    }
}

__global__ void k_degflag(const int* __restrict__ rowstart, float* __restrict__ flag) {
    int n = blockIdx.x * blockDim.x + threadIdx.x;
    if (n < N_NODES) flag[n] = (rowstart[n + 1] > rowstart[n]) ? 1.0f : 0.0f;
}

// ---------------- composite edge weights (fp32) ----------------
__global__ void k_prep(const float* __restrict__ edge_w, const float* __restrict__ edge_b,
                       const float* __restrict__ msg_w1, const float* __restrict__ msg_b1,
                       float* __restrict__ We1, float* __restrict__ bc) {
    int j = threadIdx.x;
    int c = blockIdx.x;
    int l = blockIdx.y;
    const float* w1 = msg_w1 + (size_t)l * DD * DD;
    if (c < DE) {
        float s = 0.0f;
        for (int k = 0; k < DD; k++) s += edge_w[c*DD + k] * w1[k*DD + j];
        We1[((size_t)l*DE + c)*DD + j] = s;
    } else {
        float s = msg_b1[l*DD + j];
        for (int k = 0; k < DD; k++) s += edge_b[k] * w1[k*DD + j];
        bc[l*DD + j] = s;
    }
}

// transpose fp32 [R][C] -> bf16 [C][R]
__global__ void k_tbf(const float* __restrict__ in, ushort* __restrict__ out, int R, int C) {
    int idx = blockIdx.x * 256 + threadIdx.x;
    if (idx < R * C) {
        int r = idx / C, c = idx % C;
        out[(size_t)c * R + r] = f2bf(in[idx]);
    }
}

// ---------------- MFMA GEMM: out[M,128] = A[M,128-K-slice] @ Wt^T + epi ----------------
enum { EPI_EMB = 0, EPI_BF16 = 1, EPI_FLAG = 2, EPI_GELU = 3, EPI_PART = 4, EPI_LNP = 5 };

template<int EPI, int AFP32>
__global__ __launch_bounds__(256) void k_mfma(
    const void* __restrict__ Av, int lda,
    const ushort* __restrict__ Wt, int ldw,     // Wt[n][k] bf16 (pre-transposed weights)
    const float* __restrict__ bias,
    const float* __restrict__ auxf,             // degflag (FLAG)
    const ushort* __restrict__ auxb,            // upart bf16 (LNP)
    const float* __restrict__ residf,           // node fp32 (LNP)
    const float* __restrict__ lg, const float* __restrict__ lb,
    ushort* __restrict__ outb, float* __restrict__ outf, int ldo, int M)
{
    __shared__ ushort As[64 * 136];
    __shared__ ushort Ws[128 * 136];
    int tid = threadIdx.x;
    int base = blockIdx.x * 64;
    // stage A: 64 rows x 128 bf16 (convert from fp32 if AFP32)
    if (AFP32) {
        const float* Af = (const float*)Av;
#pragma unroll
        for (int i = 0; i < 8; i++) {
            int idx = tid + i * 256;              // 2048 float4 chunks
            int r = idx >> 5, c4 = (idx & 31) * 4;
            int rg = base + r;
            float4 v = make_float4(0.f, 0.f, 0.f, 0.f);
            if (rg < M) v = *(const float4*)(Af + (size_t)rg * lda + c4);
            ushort4 o;
            o.x = f2bf(v.x); o.y = f2bf(v.y); o.z = f2bf(v.z); o.w = f2bf(v.w);
            *(ushort4*)(As + r * 136 + c4) = o;
        }
    } else {
        const ushort* Ab = (const ushort*)Av;
#pragma unroll
        for (int i = 0; i < 4; i++) {
            int c = tid + i * 256;
            int r = c >> 4, k8 = (c & 15) * 8;
            int rg = base + r;
            f4v v; v = 0.0f;
            if (rg < M) v = *(const f4v*)(Ab + (size_t)rg * lda + k8);
            *(f4v*)(As + r * 136 + k8) = v;
        }
    }
    // stage W: 128 out-rows x 128 k
#pragma unroll
    for (int i = 0; i < 8; i++) {
        int c = tid + i * 256;
        int n = c >> 4, k8 = (c & 15) * 8;
        *(f4v*)(Ws + n * 136 + k8) = *(const f4v*)(Wt + (size_t)n * ldw + k8);
    }
    __syncthreads();
    int lane = tid & 63, w = tid >> 6;
    int cq = lane & 15, quad = lane >> 4;
    bf8v a[4];
#pragma unroll
    for (int kc = 0; kc < 4; kc++)
        a[kc] = *(const bf8v*)(As + (16 * w + cq) * 136 + kc * 32 + quad * 8);
    f4v acc[8];
#pragma unroll
    for (int ct = 0; ct < 8; ct++) acc[ct] = 0.0f;
#pragma unroll
    for (int ct = 0; ct < 8; ct++) {
#pragma unroll
        for (int kc = 0; kc < 4; kc++) {
            bf8v b = *(const bf8v*)(Ws + (ct * 16 + cq) * 136 + kc * 32 + quad * 8);
            acc[ct] = __builtin_amdgcn_mfma_f32_16x16x32_bf16(a[kc], b, acc[ct], 0, 0, 0);
        }
    }
    int r0 = base + 16 * w + quad * 4;
    if (EPI == EPI_LNP) {
        float x[8][4], lgc[8], lbc[8];
#pragma unroll
        for (int ct = 0; ct < 8; ct++) {
            int col = ct * 16 + cq;
            float b_ = bias[col];
            lgc[ct] = lg[col]; lbc[ct] = lb[col];
#pragma unroll
            for (int i = 0; i < 4; i++) {
                int rg = r0 + i;
                float v = 0.0f;
                if (rg < M) v = acc[ct][i] + b_ + bf2f(auxb[(size_t)rg * 128 + col])
                               + residf[(size_t)rg * 128 + col];
                x[ct][i] = v;
            }
        }
#pragma unroll
        for (int i = 0; i < 4; i++) {
            float s = 0.0f;
#pragma unroll
            for (int ct = 0; ct < 8; ct++) s += x[ct][i];
            s += __shfl_xor(s, 1); s += __shfl_xor(s, 2);
            s += __shfl_xor(s, 4); s += __shfl_xor(s, 8);
            float m = s * (1.0f / 128.0f);
            float vv = 0.0f;
#pragma unroll
            for (int ct = 0; ct < 8; ct++) { float d = x[ct][i] - m; vv += d * d; }
            vv += __shfl_xor(vv, 1); vv += __shfl_xor(vv, 2);
            vv += __shfl_xor(vv, 4); vv += __shfl_xor(vv, 8);
            float inv = rsqrtf(vv * (1.0f / 128.0f) + 1e-5f);
            int rg = r0 + i;
            if (rg < M) {
#pragma unroll
                for (int ct = 0; ct < 8; ct++) {
                    int col = ct * 16 + cq;
                    outf[(size_t)rg * 128 + col] = (x[ct][i] - m) * inv * lgc[ct] + lbc[ct];
                }
            }
        }
    } else {
        float fl[4];
        if (EPI == EPI_FLAG) {
#pragma unroll
            for (int i = 0; i < 4; i++) { int rg = r0 + i; fl[i] = (rg < M) ? auxf[rg] : 0.0f; }
        }
#pragma unroll
        for (int ct = 0; ct < 8; ct++) {
            int col = ct * 16 + cq;
            float b_ = bias ? bias[col] : 0.0f;
#pragma unroll
            for (int i = 0; i < 4; i++) {
                int rg = r0 + i;
                if (rg >= M) continue;
                float v = acc[ct][i];
                if (EPI == EPI_FLAG) v += fl[i] * b_;
                else if (EPI == EPI_EMB || EPI == EPI_GELU) v += b_;
                if (EPI == EPI_GELU) v = gelu_f(v);
                if (EPI == EPI_EMB) outf[(size_t)rg * ldo + col] = v;
                else if (EPI == EPI_PART) outb[(size_t)rg * ldo + col] = f2bf(v);
                else outb[(size_t)rg * ldo + col] = f2bf(v);
            }
        }
    }
}

// ---------------- edge aggregation: one wave per node-slot, 4 nodes/wave ----------------
__global__ __launch_bounds__(256) void k_edge(
    const ushort* __restrict__ nodeW1, const float* __restrict__ edge_attr,
    const int* __restrict__ ei, const int* __restrict__ rowstart,
    const int* __restrict__ eord, const float* __restrict__ We1,
    const float* __restrict__ bc, ushort* __restrict__ aggh)
{
    int lane = threadIdx.x & 63;
    int wid = (blockIdx.x * 256 + threadIdx.x) >> 6;   // 0..24999
    float wA[DE], wB[DE];
#pragma unroll
    for (int c = 0; c < DE; c++) {
        float2 v = *(const float2*)(We1 + c * DD + 2 * lane);
        wA[c] = v.x; wB[c] = v.y;
    }
    float2 bc2 = *(const float2*)(bc + 2 * lane);
    for (int t = 0; t < 4; t++) {
        int n = wid * 4 + t;
        if (n >= N_NODES) return;
        int rs = rowstart[n], re = rowstart[n + 1];
        float a0 = 0.0f, a1 = 0.0f;
        for (int j = rs; j < re; j++) {
            int e = __builtin_amdgcn_readfirstlane(eord[j]);
            int src = __builtin_amdgcn_readfirstlane(ei[e]);
            const float* ea = edge_attr + (size_t)e * DE;
            uint pv = *(const uint*)(nodeW1 + (size_t)src * DD + 2 * lane);
            float x0 = bc2.x + bf2f((ushort)(pv & 0xffffu));
            float x1 = bc2.y + bf2f((ushort)(pv >> 16));
#pragma unroll
            for (int c = 0; c < DE; c++) {
                float eac = ea[c];
                x0 += eac * wA[c];
                x1 += eac * wB[c];
            }
            a0 += gelu_f(x0); a1 += gelu_f(x1);
        }
        int deg = re - rs;
        float inv = (deg > 0) ? 1.0f / (float)deg : 0.0f;
        uint o = (uint)f2bf(a0 * inv) | ((uint)f2bf(a1 * inv) << 16);
        *(uint*)(aggh + (size_t)n * DD + 2 * lane) = o;
    }
}

// ---------------- pooling (fp32 node master) ----------------
__global__ void k_pool_partial(const float* __restrict__ node, float* __restrict__ partial) {
    int seg = blockIdx.x, chunk = blockIdx.y, j = threadIdx.x;
    int segbase = seg * 14286;
    int segcnt = (seg == 6) ? 14284 : 14286;
    int per = (segcnt + 15) / 16;
    int lo = chunk * per, hi = min(lo + per, segcnt);
    float s = 0.0f;
    for (int r = lo; r < hi; r++) s += node[(size_t)(segbase + r) * DD + j];
    partial[(seg * 16 + chunk) * DD + j] = s;
}

__global__ void k_pool_final(const float* __restrict__ partial, const float* __restrict__ g,
                             const float* __restrict__ b, float* __restrict__ out) {
    __shared__ float red[128];
    int j = threadIdx.x;
    float tok[8];
    float tot = 0.0f;
#pragma unroll
    for (int s = 0; s < 7; s++) {
        float v = 0.0f;
        for (int c = 0; c < 16; c++) v += partial[(s * 16 + c) * DD + j];
        tok[1 + s] = v / ((s == 6) ? 14284.0f : 14286.0f);
        tot += v;
    }
    tok[0] = tot / 100000.0f;
    for (int t = 0; t < 8; t++) {
        float x = tok[t];
        red[j] = x; __syncthreads();
        for (int off = 64; off > 0; off >>= 1) {
            if (j < off) red[j] += red[j + off];
            __syncthreads();
        }
        float m = red[0] / 128.0f;
        __syncthreads();
        float d = x - m;
        red[j] = d * d; __syncthreads();
        for (int off = 64; off > 0; off >>= 1) {
            if (j < off) red[j] += red[j + off];
            __syncthreads();
        }
        float var = red[0] / 128.0f;
        __syncthreads();
        out[t * DD + j] = d * rsqrtf(var + 1e-5f) * g[j] + b[j];
    }
}

extern "C" void kernel_launch(void* const* d_in, const int* in_sizes, int n_in,
                              void* d_out, int out_size, void* d_ws, size_t ws_size,
                              hipStream_t stream) {
    const float* x         = (const float*)d_in[0];
    const int*   ei        = (const int*)d_in[1];
    const float* edge_attr = (const float*)d_in[2];
    const float* node_w    = (const float*)d_in[3];
    const float* node_b    = (const float*)d_in[4];
    const float* edge_w    = (const float*)d_in[5];
    const float* edge_b    = (const float*)d_in[6];
    const float* msg_w1    = (const float*)d_in[7];
    const float* msg_b1    = (const float*)d_in[8];
    const float* msg_w2    = (const float*)d_in[9];
    const float* msg_b2    = (const float*)d_in[10];
    const float* upd_w1    = (const float*)d_in[11];
    const float* upd_b1    = (const float*)d_in[12];
    const float* upd_w2    = (const float*)d_in[13];
    const float* upd_b2    = (const float*)d_in[14];
    const float* ln_g      = (const float*)d_in[15];
    const float* ln_b      = (const float*)d_in[16];
    const float* out_g     = (const float*)d_in[17];
    const float* out_b     = (const float*)d_in[18];
    float* out = (float*)d_out;

    // ---- workspace layout (~133 MB) ----
    float*  node_f  = (float*)d_ws;                        // N*128 fp32 master
    ushort* slotA   = (ushort*)(node_f + (size_t)N_NODES * DD);  // N*128 bf16: nodeW1 / B1
    ushort* R2      = slotA + (size_t)N_NODES * DD;        // N*128 bf16: aggh / T-half
    ushort* upartb  = R2 + (size_t)N_NODES * DD;           // N*128 bf16 partial u
    float*  We1     = (float*)(upartb + (size_t)N_NODES * DD);   // 3*32*128
    float*  bc      = We1 + 3 * DE * DD;                   // 3*128
    float*  partial = bc + 3 * DD;                         // 7*16*128
    float*  degflag = partial + 7 * 16 * DD;               // N
    ushort* node_wT = (ushort*)(degflag + N_NODES);        // 128*128
    ushort* msg_w1T = node_wT + DD * DD;                   // 3*128*128
    ushort* msg_w2T = msg_w1T + 3 * DD * DD;               // 3*128*128
    ushort* upd_w1T = msg_w2T + 3 * DD * DD;               // 3*256*128
    ushort* upd_w2T = upd_w1T + 3 * 256 * DD;              // 3*128*256
    int* cnt        = (int*)(upd_w2T + 3 * DD * 256);      // N
    int* rowstart   = cnt + N_NODES;                       // N+1
    int* cursor     = rowstart + N_NODES + 1;              // N
    int* eord       = cursor + N_NODES;                    // E

    hipMemsetAsync(cnt, 0, N_NODES * sizeof(int), stream);
    k_count  <<<(N_EDGES + 255) / 256, 256, 0, stream>>>(ei, cnt);
    k_scan   <<<1, 1024, 0, stream>>>(cnt, rowstart);
    k_cursor <<<(N_NODES + 255) / 256, 256, 0, stream>>>(rowstart, cursor);
    k_scatter<<<(N_EDGES + 255) / 256, 256, 0, stream>>>(ei, cursor, eord);
    k_degflag<<<(N_NODES + 255) / 256, 256, 0, stream>>>(rowstart, degflag);
    k_prep   <<<dim3(DE + 1, 3), DD, 0, stream>>>(edge_w, edge_b, msg_w1, msg_b1, We1, bc);

    // weight transposes -> bf16 [out][in]
    k_tbf<<<(DD*DD + 255)/256, 256, 0, stream>>>(node_w, node_wT, DD, DD);
    for (int l = 0; l < 3; l++) {
        k_tbf<<<(DD*DD + 255)/256, 256, 0, stream>>>(msg_w1 + (size_t)l*DD*DD, msg_w1T + (size_t)l*DD*DD, DD, DD);
        k_tbf<<<(DD*DD + 255)/256, 256, 0, stream>>>(msg_w2 + (size_t)l*DD*DD, msg_w2T + (size_t)l*DD*DD, DD, DD);
        k_tbf<<<(DD*256 + 255)/256, 256, 0, stream>>>(upd_w1 + (size_t)l*DD*256, upd_w1T + (size_t)l*256*DD, DD, 256);
        k_tbf<<<(256*DD + 255)/256, 256, 0, stream>>>(upd_w2 + (size_t)l*256*DD, upd_w2T + (size_t)l*DD*256, 256, DD);
    }

    const int GB = (N_NODES + 63) / 64;  // 1563
    // embed: node_f = x @ node_w + node_b  (fp32 A, fp32 out)
    k_mfma<EPI_EMB, 1><<<GB, 256, 0, stream>>>(x, DD, node_wT, DD, node_b,
        nullptr, nullptr, nullptr, nullptr, nullptr, nullptr, node_f, DD, N_NODES);

    for (int l = 0; l < 3; l++) {
        // a: nodeW1 = node @ msg_w1   (fp32 A -> bf16 out)
        k_mfma<EPI_BF16, 1><<<GB, 256, 0, stream>>>(node_f, DD, msg_w1T + (size_t)l*DD*DD, DD,
            nullptr, nullptr, nullptr, nullptr, nullptr, nullptr, slotA, nullptr, DD, N_NODES);
        // b: edge aggregation -> R2 (agg bf16)
        k_edge<<<6250, 256, 0, stream>>>(slotA, edge_attr, ei, rowstart, eord,
            We1 + (size_t)l*DE*DD, bc + (size_t)l*DD, R2);
        // c: B1 = agg @ msg_w2 + flag*b2 -> slotA
        k_mfma<EPI_FLAG, 0><<<GB, 256, 0, stream>>>(R2, DD, msg_w2T + (size_t)l*DD*DD, DD,
            msg_b2 + (size_t)l*DD, degflag, nullptr, nullptr, nullptr, nullptr, slotA, nullptr, DD, N_NODES);
        // d1: T1 = gelu(B1 @ upd_w1[:, :128] + b) -> R2
        k_mfma<EPI_GELU, 0><<<GB, 256, 0, stream>>>(slotA, DD, upd_w1T + (size_t)l*256*DD, DD,
            upd_b1 + (size_t)l*256, nullptr, nullptr, nullptr, nullptr, nullptr, R2, nullptr, DD, N_NODES);
        // e: upart = T1 @ upd_w2[:128, :] -> upartb (bf16)
        k_mfma<EPI_PART, 0><<<GB, 256, 0, stream>>>(R2, DD, upd_w2T + (size_t)l*DD*256, 256,
            nullptr, nullptr, nullptr, nullptr, nullptr, nullptr, upartb, nullptr, DD, N_NODES);
        // d2: T2 = gelu(B1 @ upd_w1[:, 128:] + b) -> R2
        k_mfma<EPI_GELU, 0><<<GB, 256, 0, stream>>>(slotA, DD, upd_w1T + (size_t)l*256*DD + 128*DD, DD,
            upd_b1 + (size_t)l*256 + 128, nullptr, nullptr, nullptr, nullptr, nullptr, R2, nullptr, DD, N_NODES);
        // f: node_f = LN(node_f + upart + T2 @ upd_w2[128:, :] + bu2)
        k_mfma<EPI_LNP, 0><<<GB, 256, 0, stream>>>(R2, DD, upd_w2T + (size_t)l*DD*256 + 128, 256,
            upd_b2 + (size_t)l*DD, nullptr, upartb, node_f,
            ln_g + (size_t)l*DD, ln_b + (size_t)l*DD, nullptr, node_f, DD, N_NODES);
    }

    k_pool_partial<<<dim3(7, 16), DD, 0, stream>>>(node_f, partial);
    k_pool_final  <<<1, DD, 0, stream>>>(partial, out_g, out_b, out);
}